// Round 4
// baseline (560.926 us; speedup 1.0000x reference)
//
#include <hip/hip_runtime.h>

typedef __bf16 bf16;
typedef __bf16 bf16x8 __attribute__((ext_vector_type(8)));
typedef __bf16 bf16x4 __attribute__((ext_vector_type(4)));
typedef float floatx4 __attribute__((ext_vector_type(4)));
typedef unsigned int uint4t __attribute__((ext_vector_type(4)));

typedef __attribute__((address_space(1))) void gvoid;
typedef __attribute__((address_space(3))) void lvoid;
#define ASYNC_COPY16(gp, lp) \
  __builtin_amdgcn_global_load_lds((gvoid*)(gp), (lvoid*)(lp), 16, 0, 0)

#define NB 4
#define SQ 2048
#define DMODEL 1024
#define NH 16
#define HD 64
#define MTOK (NB * SQ)   // 8192
#define LOG2E 1.44269504088896f

// workspace layout (bytes)
#define XB_OFF 0ull                        // bf16 X       [8192][1024]  16 MB
#define WT_OFF (16ull * 1024 * 1024)       // bf16 W^T x3  [3][1024][1024] 6 MB
#define Q_OFF  (22ull * 1024 * 1024)       // bf16 Q [64][2048][64]  16 MB (pre-scaled 0.125*log2e)
#define K_OFF  (38ull * 1024 * 1024)       // bf16 K [64][2048][64]  16 MB
#define V_OFF  (54ull * 1024 * 1024)       // bf16 V^T [64][64][2048] 16 MB
#define FLG_OFF (70ull * 1024 * 1024)      // int flags [4][16][32]   8 KB

// ------------------------------------------------- prep: convert X + transpose W + mask scan
__global__ __launch_bounds__(256) void prep(
    const float* __restrict__ x, bf16* __restrict__ xb,
    const float* __restrict__ w0, const float* __restrict__ w1,
    const float* __restrict__ w2, bf16* __restrict__ wt,
    const float* __restrict__ mask, int* __restrict__ flags) {
  __shared__ float tlds[32][33];
  int blk = blockIdx.x;
  int t = threadIdx.x;
  if (blk < 8192) {
    int i = blk * 256 + t;
    float4 v = ((const float4*)x)[i];
    bf16x4 o;
    o[0] = (bf16)v.x; o[1] = (bf16)v.y; o[2] = (bf16)v.z; o[3] = (bf16)v.w;
    ((bf16x4*)xb)[i] = o;
  } else if (blk < 11264) {
    int tidx = blk - 8192;            // 0..3071
    int z = tidx >> 10;               // 0..2
    int rem = tidx & 1023;
    int kb = ((rem >> 5) & 31) * 32, nb = (rem & 31) * 32;
    const float* w = (z == 0) ? w0 : (z == 1) ? w1 : w2;
    bf16* out = wt + (size_t)z * DMODEL * DMODEL;
    int tx = t & 31, ty = t >> 5;     // 32 x 8
#pragma unroll
    for (int i = 0; i < 4; i++)
      tlds[ty + 8 * i][tx] = w[(size_t)(kb + ty + 8 * i) * DMODEL + nb + tx];
    __syncthreads();
#pragma unroll
    for (int i = 0; i < 4; i++)
      out[(size_t)(nb + ty + 8 * i) * DMODEL + kb + tx] = (bf16)tlds[tx][ty + 8 * i];
  } else {
    int midx = blk - 11264;           // 0..2047
    int kt = midx & 31, qt = (midx >> 5) & 15, b = midx >> 9;
    const float* mb = mask + ((size_t)b * SQ + qt * 128) * SQ + kt * 64;
    int row = t >> 1, half = t & 1;
    const float4* p = (const float4*)(mb + (size_t)row * SQ + half * 32);
    bool nz = false;
#pragma unroll
    for (int i = 0; i < 8; i++) {
      float4 vv = p[i];
      nz |= (vv.x != 0.f) | (vv.y != 0.f) | (vv.z != 0.f) | (vv.w != 0.f);
    }
    int* acc = (int*)tlds;
    if (t == 0) acc[0] = 0;
    __syncthreads();
    unsigned long long m = __ballot(nz);
    if ((t & 63) == 0 && m) atomicOr(acc, 1);
    __syncthreads();
    if (t == 0) flags[(b * 16 + qt) * 32 + kt] = acc[0];
  }
}

// ---------------------------------------------------------------- QKV GEMM (pure)
// 1536 blocks = 64 mt x 24 nt; XCD band mapping (id&7 -> mt band) for L2 reuse.
#define BK 64
__global__ __launch_bounds__(256) void qkv(
    const bf16* __restrict__ xb,   // [8192][1024]
    const bf16* __restrict__ wt,   // [3][1024 n][1024 k]
    const float* __restrict__ biasq, const float* __restrict__ biask,
    const float* __restrict__ biasv,
    bf16* __restrict__ q, bf16* __restrict__ k, bf16* __restrict__ v) {
  __shared__ bf16 As[128 * BK];
  __shared__ bf16 Bs[128 * BK];

  int id = blockIdx.x;              // 0..1535
  int local = id >> 3;              // 0..191
  int mt = ((id & 7) << 3) | (local & 7);  // 0..63, band per XCD
  int nt = local >> 3;              // 0..23
  int t = threadIdx.x;

  int mat = nt >> 3;                // 0=Q 1=K 2=V
  int nbase = (nt & 7) * 128;
  const bf16* wmat = wt + (size_t)mat * DMODEL * DMODEL;
  const float* bias = (mat == 0) ? biasq : (mat == 1) ? biask : biasv;
  bf16* outp = (mat == 0) ? q : (mat == 1) ? k : v;

  int lane = t & 63, wid = t >> 6;
  int quad = lane >> 4, l16 = lane & 15;
  int wm = (wid & 1) * 64, wn = (wid >> 1) * 64;
  int xq = quad ^ (l16 & 7);        // swizzled chunk index

  floatx4 acc[4][4] = {};

  for (int kb = 0; kb < DMODEL; kb += BK) {
    __syncthreads();
#pragma unroll
    for (int p = 0; p < 4; p++) {
      int i2 = p * 256 + t;
      int row = i2 >> 3;
      int gch = (i2 ^ row) & 7;
      ASYNC_COPY16(xb + (size_t)(mt * 128 + row) * DMODEL + kb + gch * 8,
                   As + i2 * 8);
      ASYNC_COPY16(wmat + (size_t)(nbase + row) * DMODEL + kb + gch * 8,
                   Bs + i2 * 8);
    }
    __syncthreads();

#pragma unroll
    for (int kc = 0; kc < BK; kc += 32) {
      int xc = (kc >> 3) ^ xq;
      bf16x8 af[4], bfr[4];
#pragma unroll
      for (int mi = 0; mi < 4; mi++)
        af[mi] = *(const bf16x8*)(As + (wm + mi * 16 + l16) * BK + xc * 8);
#pragma unroll
      for (int ni = 0; ni < 4; ni++)
        bfr[ni] = *(const bf16x8*)(Bs + (wn + ni * 16 + l16) * BK + xc * 8);
      if (mat < 2) {   // transposed: D[n][m], col=l16=token
#pragma unroll
        for (int mi = 0; mi < 4; mi++)
#pragma unroll
          for (int ni = 0; ni < 4; ni++)
            acc[mi][ni] = __builtin_amdgcn_mfma_f32_16x16x32_bf16(
                bfr[ni], af[mi], acc[mi][ni], 0, 0, 0);
      } else {         // normal: D[m][n], col=l16=feature
#pragma unroll
        for (int mi = 0; mi < 4; mi++)
#pragma unroll
          for (int ni = 0; ni < 4; ni++)
            acc[mi][ni] = __builtin_amdgcn_mfma_f32_16x16x32_bf16(
                af[mi], bfr[ni], acc[mi][ni], 0, 0, 0);
      }
    }
  }

  int mg0 = mt * 128 + wm;
  if (mat < 2) {
    float qscale = (mat == 0) ? 0.125f * LOG2E : 1.0f;
#pragma unroll
    for (int ni = 0; ni < 4; ni++) {
      int n0 = nbase + wn + ni * 16 + quad * 4;
      int h = n0 >> 6, d0 = n0 & 63;
      float4 bv4 = *(const float4*)(bias + n0);
#pragma unroll
      for (int mi = 0; mi < 4; mi++) {
        int m = mg0 + mi * 16 + l16;
        int b = m >> 11, s = m & 2047;
        bf16x4 pk;
        pk[0] = (bf16)((acc[mi][ni][0] + bv4.x) * qscale);
        pk[1] = (bf16)((acc[mi][ni][1] + bv4.y) * qscale);
        pk[2] = (bf16)((acc[mi][ni][2] + bv4.z) * qscale);
        pk[3] = (bf16)((acc[mi][ni][3] + bv4.w) * qscale);
        *(bf16x4*)(outp + (((size_t)(b * NH + h) * SQ + s) << 6) + d0) = pk;
      }
    }
  } else {
#pragma unroll
    for (int ni = 0; ni < 4; ni++) {
      int n = nbase + wn + ni * 16 + l16;
      int h = n >> 6, d = n & 63;
      float bv_ = bias[n];
#pragma unroll
      for (int mi = 0; mi < 4; mi++) {
        int m0 = mg0 + mi * 16 + quad * 4;
        int b = m0 >> 11, s = m0 & 2047;
        bf16x4 pk;
#pragma unroll
        for (int r = 0; r < 4; r++) pk[r] = (bf16)(acc[mi][ni][r] + bv_);
        *(bf16x4*)(outp + (((size_t)(b * NH + h) * HD + d) << 11) + s) = pk;
      }
    }
  }
}

// ---------------------------------------------------------------- attention
// Single-buffered K/V staging. P transpose IN-REGISTER via
// v_permlane32_swap + v_permlane16_swap (vdst-high <-> vsrc-low semantics:
// combined [d_lo,d_hi,s_lo,s_hi] -> [d_lo,s_lo,d_hi,s_hi]). Operand order:
// vdst = k-even-block register (a), vsrc = k-odd-block (b); after both swaps
// lane[5:4] carries k[4:3] and regs carry (k5,k2,k1) = PV B-operand layout.
// (Round-2 failure was the reversed operand order.)
__global__ __launch_bounds__(256, 6) void attn(
    const bf16* __restrict__ Q,     // [64][2048][64], pre-scaled by 0.125*log2e
    const bf16* __restrict__ K,     // [64][2048][64]
    const bf16* __restrict__ Vt,    // [64][64][2048]
    const float* __restrict__ mask, // [4][2048][2048]
    const int* __restrict__ flags,  // [4][16][32]
    float* __restrict__ out) {      // [4][2048][1024]
  __shared__ bf16 Ks[64 * 64];      // [s][d], swizzled
  __shared__ bf16 Vs[64 * 64];      // [d][s], swizzled

  int bh = blockIdx.x;              // 0..63 (all qt of one head on one XCD)
  int qt = blockIdx.y;
  int b = bh >> 4, h = bh & 15;
  int t = threadIdx.x, lane = t & 63, wid = t >> 6;
  int quad = lane >> 4, l16 = lane & 15;
  int q0 = qt * 128 + wid * 32;

  const bf16* Qp = Q + ((size_t)bh * SQ + q0) * HD;
  const bf16* Kp = K + (size_t)bh * SQ * HD;
  const bf16* Vp = Vt + (size_t)bh * HD * SQ;
  const float* mp = mask + ((size_t)b * SQ + q0) * SQ;
  const int* flg = flags + (b * 16 + qt) * 32;

  bf16x8 qa[2][2];
#pragma unroll
  for (int m = 0; m < 2; m++) {
    const bf16* qr = Qp + (size_t)(m * 16 + l16) * HD;
    qa[m][0] = *(const bf16x8*)(qr + quad * 8);
    qa[m][1] = *(const bf16x8*)(qr + 32 + quad * 8);
  }

  floatx4 o[2][4] = {};             // O^T[d][q]: col=l16=q, row=quad*4+r=d
  float li[2] = {0.f, 0.f};
  int xq = quad ^ (l16 & 7);

  for (int kb = 0, kti = 0; kb < SQ; kb += 64, kti++) {
    __syncthreads();
#pragma unroll
    for (int p = 0; p < 2; p++) {
      int idx = p * 256 + t;        // 0..511
      int row = idx >> 3;
      int gch = (idx ^ row) & 7;
      ASYNC_COPY16(Kp + (size_t)(kb + row) * HD + gch * 8, Ks + idx * 8);
      ASYNC_COPY16(Vp + (size_t)row * SQ + kb + gch * 8, Vs + idx * 8);
    }
    __syncthreads();
    int flag = flg[kti];

    // Phase A: S^T for both m tiles; xs[m][kt][r] holds k = 16kt + 4quad + r
    float xs[2][4][4];
    __builtin_amdgcn_s_setprio(1);
#pragma unroll
    for (int kt = 0; kt < 4; kt++) {
      const bf16* kr = Ks + (kt * 16 + l16) * 64;
      bf16x8 k0 = *(const bf16x8*)(kr + xq * 8);
      bf16x8 k1 = *(const bf16x8*)(kr + (xq ^ 4) * 8);
      floatx4 z0 = {}, z1 = {};
      z0 = __builtin_amdgcn_mfma_f32_16x16x32_bf16(k0, qa[0][0], z0, 0, 0, 0);
      z0 = __builtin_amdgcn_mfma_f32_16x16x32_bf16(k1, qa[0][1], z0, 0, 0, 0);
      z1 = __builtin_amdgcn_mfma_f32_16x16x32_bf16(k0, qa[1][0], z1, 0, 0, 0);
      z1 = __builtin_amdgcn_mfma_f32_16x16x32_bf16(k1, qa[1][1], z1, 0, 0, 0);
#pragma unroll
      for (int r = 0; r < 4; r++) { xs[0][kt][r] = z0[r]; xs[1][kt][r] = z1[r]; }
    }
    __builtin_amdgcn_s_setprio(0);
    if (flag) {
#pragma unroll
      for (int m = 0; m < 2; m++)
#pragma unroll
        for (int kt = 0; kt < 4; kt++)
#pragma unroll
          for (int r = 0; r < 4; r++)
            xs[m][kt][r] = __builtin_fmaf(
                mp[(size_t)(m * 16 + l16) * SQ + kb + kt * 16 + quad * 4 + r],
                LOG2E, xs[m][kt][r]);
    }

    // Phase B: exp2 -> cvt_pk bf16 pairs -> in-register quad transpose.
    // u[kt][p]: reg bits (k5=kt>>1, k4=kt&1, k1=p), halves k0, lane[5:4]=k[3:2].
    // swap(vdst=a, vsrc=b) twice: lane[5:4] becomes k[4:3], regs (k5,k2,k1).
    bf16x8 pb[2][2];
#pragma unroll
    for (int m = 0; m < 2; m++) {
      float sum = 0.f;
      unsigned int u[4][2];
#pragma unroll
      for (int kt = 0; kt < 4; kt++) {
        float e0 = __builtin_amdgcn_exp2f(xs[m][kt][0]);
        float e1 = __builtin_amdgcn_exp2f(xs[m][kt][1]);
        float e2 = __builtin_amdgcn_exp2f(xs[m][kt][2]);
        float e3 = __builtin_amdgcn_exp2f(xs[m][kt][3]);
        sum += (e0 + e1) + (e2 + e3);
        asm("v_cvt_pk_bf16_f32 %0, %1, %2" : "=v"(u[kt][0]) : "v"(e0), "v"(e1));
        asm("v_cvt_pk_bf16_f32 %0, %1, %2" : "=v"(u[kt][1]) : "v"(e2), "v"(e3));
      }
      li[m] += sum;
#pragma unroll
      for (int f = 0; f < 2; f++) {
        unsigned int a0 = u[2 * f][0], b0 = u[2 * f + 1][0];
        unsigned int a1 = u[2 * f][1], b1 = u[2 * f + 1][1];
        // step 1: a(high32) <-> b(low32): a=[a_lo,b_lo] (k3=0), b=[a_hi,b_hi] (k3=1), lane5=k4
        asm("v_permlane32_swap_b32 %0, %1" : "+v"(a0), "+v"(b0));
        asm("v_permlane32_swap_b32 %0, %1" : "+v"(a1), "+v"(b1));
        // step 2: per-32 a(hi16) <-> b(lo16): a: k2=0, b: k2=1, lane4=k3
        asm("v_permlane16_swap_b32 %0, %1" : "+v"(a0), "+v"(b0));
        asm("v_permlane16_swap_b32 %0, %1" : "+v"(a1), "+v"(b1));
        uint4t w;
        w[0] = a0; w[1] = a1; w[2] = b0; w[3] = b1;
        pb[m][f] = __builtin_bit_cast(bf16x8, w);
      }
    }

    // Phase C: O^T += V^T x P^T
    __builtin_amdgcn_s_setprio(1);
#pragma unroll
    for (int dt = 0; dt < 4; dt++) {
      const bf16* vr = Vs + (dt * 16 + l16) * 64;
      bf16x8 v0 = *(const bf16x8*)(vr + xq * 8);
      bf16x8 v1 = *(const bf16x8*)(vr + (xq ^ 4) * 8);
      o[0][dt] = __builtin_amdgcn_mfma_f32_16x16x32_bf16(v0, pb[0][0], o[0][dt], 0, 0, 0);
      o[0][dt] = __builtin_amdgcn_mfma_f32_16x16x32_bf16(v1, pb[0][1], o[0][dt], 0, 0, 0);
      o[1][dt] = __builtin_amdgcn_mfma_f32_16x16x32_bf16(v0, pb[1][0], o[1][dt], 0, 0, 0);
      o[1][dt] = __builtin_amdgcn_mfma_f32_16x16x32_bf16(v1, pb[1][1], o[1][dt], 0, 0, 0);
    }
    __builtin_amdgcn_s_setprio(0);
  }
#pragma unroll
  for (int m = 0; m < 2; m++) {
    li[m] += __shfl_xor(li[m], 16, 64);
    li[m] += __shfl_xor(li[m], 32, 64);
  }
#pragma unroll
  for (int m = 0; m < 2; m++) {
    float inv = 1.0f / li[m];
    float* op = out + ((size_t)b * SQ + q0 + m * 16 + l16) * DMODEL + h * HD;
#pragma unroll
    for (int dt = 0; dt < 4; dt++)
#pragma unroll
      for (int r = 0; r < 4; r++)
        op[dt * 16 + quad * 4 + r] = o[m][dt][r] * inv;
  }
}

// ---------------------------------------------------------------- launcher
extern "C" void kernel_launch(void* const* d_in, const int* in_sizes, int n_in,
                              void* d_out, int out_size, void* d_ws, size_t ws_size,
                              hipStream_t stream) {
  (void)in_sizes; (void)n_in; (void)out_size; (void)ws_size;
  const float* hs   = (const float*)d_in[0];
  const float* mask = (const float*)d_in[1];
  const float* Wq   = (const float*)d_in[2];
  const float* bq   = (const float*)d_in[3];
  const float* Wk   = (const float*)d_in[4];
  const float* bk   = (const float*)d_in[5];
  const float* Wv   = (const float*)d_in[6];
  const float* bv   = (const float*)d_in[7];
  float* out = (float*)d_out;
  char* ws = (char*)d_ws;
  bf16* xb = (bf16*)(ws + XB_OFF);
  bf16* wt = (bf16*)(ws + WT_OFF);
  bf16* q  = (bf16*)(ws + Q_OFF);
  bf16* k  = (bf16*)(ws + K_OFF);
  bf16* v  = (bf16*)(ws + V_OFF);
  int* flg = (int*)(ws + FLG_OFF);

  prep<<<8192 + 3072 + 2048, 256, 0, stream>>>(hs, xb, Wq, Wk, Wv, wt, mask, flg);
  qkv<<<1536, 256, 0, stream>>>(xb, wt, bq, bk, bv, q, k, v);
  attn<<<dim3(64, 16), 256, 0, stream>>>(q, k, v, mask, flg, out);
}

// Round 5
// 294.797 us; speedup vs baseline: 1.9028x; 1.9028x over previous
//
#include <hip/hip_runtime.h>

typedef __bf16 bf16;
typedef __bf16 bf16x8 __attribute__((ext_vector_type(8)));
typedef __bf16 bf16x4 __attribute__((ext_vector_type(4)));
typedef float floatx4 __attribute__((ext_vector_type(4)));
typedef unsigned int uint4t __attribute__((ext_vector_type(4)));

typedef __attribute__((address_space(1))) void gvoid;
typedef __attribute__((address_space(3))) void lvoid;
#define ASYNC_COPY16(gp, lp) \
  __builtin_amdgcn_global_load_lds((gvoid*)(gp), (lvoid*)(lp), 16, 0, 0)

#define NB 4
#define SQ 2048
#define DMODEL 1024
#define NH 16
#define HD 64
#define MTOK (NB * SQ)   // 8192
#define LOG2E 1.44269504088896f

// workspace layout (bytes)
#define XB_OFF 0ull                        // bf16 X       [8192][1024]  16 MB
#define WT_OFF (16ull * 1024 * 1024)       // bf16 W^T x3  [3][1024][1024] 6 MB
#define Q_OFF  (22ull * 1024 * 1024)       // bf16 Q [64][2048][64]  16 MB (pre-scaled 0.125*log2e)
#define K_OFF  (38ull * 1024 * 1024)       // bf16 K [64][2048][64]  16 MB
#define V_OFF  (54ull * 1024 * 1024)       // bf16 V^T [64][64][2048] 16 MB
#define FLG_OFF (70ull * 1024 * 1024)      // int flags [4][16][32]   8 KB

// ------------------------------------------------- prep: convert X + transpose W + mask scan
__global__ __launch_bounds__(256) void prep(
    const float* __restrict__ x, bf16* __restrict__ xb,
    const float* __restrict__ w0, const float* __restrict__ w1,
    const float* __restrict__ w2, bf16* __restrict__ wt,
    const float* __restrict__ mask, int* __restrict__ flags) {
  __shared__ float tlds[32][33];
  int blk = blockIdx.x;
  int t = threadIdx.x;
  if (blk < 8192) {
    int i = blk * 256 + t;
    float4 v = ((const float4*)x)[i];
    bf16x4 o;
    o[0] = (bf16)v.x; o[1] = (bf16)v.y; o[2] = (bf16)v.z; o[3] = (bf16)v.w;
    ((bf16x4*)xb)[i] = o;
  } else if (blk < 11264) {
    int tidx = blk - 8192;            // 0..3071
    int z = tidx >> 10;               // 0..2
    int rem = tidx & 1023;
    int kb = ((rem >> 5) & 31) * 32, nb = (rem & 31) * 32;
    const float* w = (z == 0) ? w0 : (z == 1) ? w1 : w2;
    bf16* out = wt + (size_t)z * DMODEL * DMODEL;
    int tx = t & 31, ty = t >> 5;     // 32 x 8
#pragma unroll
    for (int i = 0; i < 4; i++)
      tlds[ty + 8 * i][tx] = w[(size_t)(kb + ty + 8 * i) * DMODEL + nb + tx];
    __syncthreads();
#pragma unroll
    for (int i = 0; i < 4; i++)
      out[(size_t)(nb + ty + 8 * i) * DMODEL + kb + tx] = (bf16)tlds[tx][ty + 8 * i];
  } else {
    int midx = blk - 11264;           // 0..2047
    int kt = midx & 31, qt = (midx >> 5) & 15, b = midx >> 9;
    const float* mb = mask + ((size_t)b * SQ + qt * 128) * SQ + kt * 64;
    int row = t >> 1, half = t & 1;
    const float4* p = (const float4*)(mb + (size_t)row * SQ + half * 32);
    bool nz = false;
#pragma unroll
    for (int i = 0; i < 8; i++) {
      float4 vv = p[i];
      nz |= (vv.x != 0.f) | (vv.y != 0.f) | (vv.z != 0.f) | (vv.w != 0.f);
    }
    int* acc = (int*)tlds;
    if (t == 0) acc[0] = 0;
    __syncthreads();
    unsigned long long m = __ballot(nz);
    if ((t & 63) == 0 && m) atomicOr(acc, 1);
    __syncthreads();
    if (t == 0) flags[(b * 16 + qt) * 32 + kt] = acc[0];
  }
}

// ---------------------------------------------------------------- QKV GEMM (pure)
// 1536 blocks = 64 mt x 24 nt; XCD band mapping (id&7 -> mt band) for L2 reuse.
#define BK 64
__global__ __launch_bounds__(256) void qkv(
    const bf16* __restrict__ xb,   // [8192][1024]
    const bf16* __restrict__ wt,   // [3][1024 n][1024 k]
    const float* __restrict__ biasq, const float* __restrict__ biask,
    const float* __restrict__ biasv,
    bf16* __restrict__ q, bf16* __restrict__ k, bf16* __restrict__ v) {
  __shared__ bf16 As[128 * BK];
  __shared__ bf16 Bs[128 * BK];

  int id = blockIdx.x;              // 0..1535
  int local = id >> 3;              // 0..191
  int mt = ((id & 7) << 3) | (local & 7);  // 0..63, band per XCD
  int nt = local >> 3;              // 0..23
  int t = threadIdx.x;

  int mat = nt >> 3;                // 0=Q 1=K 2=V
  int nbase = (nt & 7) * 128;
  const bf16* wmat = wt + (size_t)mat * DMODEL * DMODEL;
  const float* bias = (mat == 0) ? biasq : (mat == 1) ? biask : biasv;
  bf16* outp = (mat == 0) ? q : (mat == 1) ? k : v;

  int lane = t & 63, wid = t >> 6;
  int quad = lane >> 4, l16 = lane & 15;
  int wm = (wid & 1) * 64, wn = (wid >> 1) * 64;
  int xq = quad ^ (l16 & 7);        // swizzled chunk index

  floatx4 acc[4][4] = {};

  for (int kb = 0; kb < DMODEL; kb += BK) {
    __syncthreads();
#pragma unroll
    for (int p = 0; p < 4; p++) {
      int i2 = p * 256 + t;
      int row = i2 >> 3;
      int gch = (i2 ^ row) & 7;
      ASYNC_COPY16(xb + (size_t)(mt * 128 + row) * DMODEL + kb + gch * 8,
                   As + i2 * 8);
      ASYNC_COPY16(wmat + (size_t)(nbase + row) * DMODEL + kb + gch * 8,
                   Bs + i2 * 8);
    }
    __syncthreads();

#pragma unroll
    for (int kc = 0; kc < BK; kc += 32) {
      int xc = (kc >> 3) ^ xq;
      bf16x8 af[4], bfr[4];
#pragma unroll
      for (int mi = 0; mi < 4; mi++)
        af[mi] = *(const bf16x8*)(As + (wm + mi * 16 + l16) * BK + xc * 8);
#pragma unroll
      for (int ni = 0; ni < 4; ni++)
        bfr[ni] = *(const bf16x8*)(Bs + (wn + ni * 16 + l16) * BK + xc * 8);
      if (mat < 2) {   // transposed: D[n][m], col=l16=token
#pragma unroll
        for (int mi = 0; mi < 4; mi++)
#pragma unroll
          for (int ni = 0; ni < 4; ni++)
            acc[mi][ni] = __builtin_amdgcn_mfma_f32_16x16x32_bf16(
                bfr[ni], af[mi], acc[mi][ni], 0, 0, 0);
      } else {         // normal: D[m][n], col=l16=feature
#pragma unroll
        for (int mi = 0; mi < 4; mi++)
#pragma unroll
          for (int ni = 0; ni < 4; ni++)
            acc[mi][ni] = __builtin_amdgcn_mfma_f32_16x16x32_bf16(
                af[mi], bfr[ni], acc[mi][ni], 0, 0, 0);
      }
    }
  }

  int mg0 = mt * 128 + wm;
  if (mat < 2) {
    float qscale = (mat == 0) ? 0.125f * LOG2E : 1.0f;
#pragma unroll
    for (int ni = 0; ni < 4; ni++) {
      int n0 = nbase + wn + ni * 16 + quad * 4;
      int h = n0 >> 6, d0 = n0 & 63;
      float4 bv4 = *(const float4*)(bias + n0);
#pragma unroll
      for (int mi = 0; mi < 4; mi++) {
        int m = mg0 + mi * 16 + l16;
        int b = m >> 11, s = m & 2047;
        bf16x4 pk;
        pk[0] = (bf16)((acc[mi][ni][0] + bv4.x) * qscale);
        pk[1] = (bf16)((acc[mi][ni][1] + bv4.y) * qscale);
        pk[2] = (bf16)((acc[mi][ni][2] + bv4.z) * qscale);
        pk[3] = (bf16)((acc[mi][ni][3] + bv4.w) * qscale);
        *(bf16x4*)(outp + (((size_t)(b * NH + h) * SQ + s) << 6) + d0) = pk;
      }
    }
  } else {
#pragma unroll
    for (int ni = 0; ni < 4; ni++) {
      int n = nbase + wn + ni * 16 + l16;
      int h = n >> 6, d = n & 63;
      float bv_ = bias[n];
#pragma unroll
      for (int mi = 0; mi < 4; mi++) {
        int m0 = mg0 + mi * 16 + quad * 4;
        int b = m0 >> 11, s = m0 & 2047;
        bf16x4 pk;
#pragma unroll
        for (int r = 0; r < 4; r++) pk[r] = (bf16)(acc[mi][ni][r] + bv_);
        *(bf16x4*)(outp + (((size_t)(b * NH + h) * HD + d) << 11) + s) = pk;
      }
    }
  }
}

// ---------------------------------------------------------------- attention
// Single-buffered K/V staging. P transpose IN-REGISTER via
// v_permlane32_swap + v_permlane16_swap (correct operand order verified in
// round 3: absmax OK, bank conflicts 0). launch_bounds(256,4): VGPR budget
// 128 — round 3's (256,6) capped at ~85 and spilled the o[2][4] accumulators
// to scratch (FETCH+WRITE 1.6 GB, 356us). 16.4KB LDS -> wave-limit-bound at
// 4 blocks/CU (50% occupancy).
__global__ __launch_bounds__(256, 4) void attn(
    const bf16* __restrict__ Q,     // [64][2048][64], pre-scaled by 0.125*log2e
    const bf16* __restrict__ K,     // [64][2048][64]
    const bf16* __restrict__ Vt,    // [64][64][2048]
    const float* __restrict__ mask, // [4][2048][2048]
    const int* __restrict__ flags,  // [4][16][32]
    float* __restrict__ out) {      // [4][2048][1024]
  __shared__ bf16 Ks[64 * 64];      // [s][d], swizzled
  __shared__ bf16 Vs[64 * 64];      // [d][s], swizzled

  int bh = blockIdx.x;              // 0..63 (all qt of one head on one XCD)
  int qt = blockIdx.y;
  int b = bh >> 4, h = bh & 15;
  int t = threadIdx.x, lane = t & 63, wid = t >> 6;
  int quad = lane >> 4, l16 = lane & 15;
  int q0 = qt * 128 + wid * 32;

  const bf16* Qp = Q + ((size_t)bh * SQ + q0) * HD;
  const bf16* Kp = K + (size_t)bh * SQ * HD;
  const bf16* Vp = Vt + (size_t)bh * HD * SQ;
  const float* mp = mask + ((size_t)b * SQ + q0) * SQ;
  const int* flg = flags + (b * 16 + qt) * 32;

  bf16x8 qa[2][2];
#pragma unroll
  for (int m = 0; m < 2; m++) {
    const bf16* qr = Qp + (size_t)(m * 16 + l16) * HD;
    qa[m][0] = *(const bf16x8*)(qr + quad * 8);
    qa[m][1] = *(const bf16x8*)(qr + 32 + quad * 8);
  }

  floatx4 o[2][4] = {};             // O^T[d][q]: col=l16=q, row=quad*4+r=d
  float li[2] = {0.f, 0.f};
  int xq = quad ^ (l16 & 7);

  for (int kb = 0, kti = 0; kb < SQ; kb += 64, kti++) {
    __syncthreads();
#pragma unroll
    for (int p = 0; p < 2; p++) {
      int idx = p * 256 + t;        // 0..511
      int row = idx >> 3;
      int gch = (idx ^ row) & 7;
      ASYNC_COPY16(Kp + (size_t)(kb + row) * HD + gch * 8, Ks + idx * 8);
      ASYNC_COPY16(Vp + (size_t)row * SQ + kb + gch * 8, Vs + idx * 8);
    }
    __syncthreads();
    int flag = flg[kti];

    // Phase A: S^T for both m tiles; xs[m][kt][r] holds k = 16kt + 4quad + r
    float xs[2][4][4];
    __builtin_amdgcn_s_setprio(1);
#pragma unroll
    for (int kt = 0; kt < 4; kt++) {
      const bf16* kr = Ks + (kt * 16 + l16) * 64;
      bf16x8 k0 = *(const bf16x8*)(kr + xq * 8);
      bf16x8 k1 = *(const bf16x8*)(kr + (xq ^ 4) * 8);
      floatx4 z0 = {}, z1 = {};
      z0 = __builtin_amdgcn_mfma_f32_16x16x32_bf16(k0, qa[0][0], z0, 0, 0, 0);
      z0 = __builtin_amdgcn_mfma_f32_16x16x32_bf16(k1, qa[0][1], z0, 0, 0, 0);
      z1 = __builtin_amdgcn_mfma_f32_16x16x32_bf16(k0, qa[1][0], z1, 0, 0, 0);
      z1 = __builtin_amdgcn_mfma_f32_16x16x32_bf16(k1, qa[1][1], z1, 0, 0, 0);
#pragma unroll
      for (int r = 0; r < 4; r++) { xs[0][kt][r] = z0[r]; xs[1][kt][r] = z1[r]; }
    }
    __builtin_amdgcn_s_setprio(0);
    if (flag) {
#pragma unroll
      for (int m = 0; m < 2; m++)
#pragma unroll
        for (int kt = 0; kt < 4; kt++)
#pragma unroll
          for (int r = 0; r < 4; r++)
            xs[m][kt][r] = __builtin_fmaf(
                mp[(size_t)(m * 16 + l16) * SQ + kb + kt * 16 + quad * 4 + r],
                LOG2E, xs[m][kt][r]);
    }

    // Phase B: exp2 -> cvt_pk bf16 pairs -> in-register quad transpose.
    // u[kt][p]: reg bits (k5=kt>>1, k4=kt&1, k1=p), halves k0, lane[5:4]=k[3:2].
    // swap(vdst=a, vsrc=b) twice: lane[5:4] becomes k[4:3], regs (k5,k2,k1).
    bf16x8 pb[2][2];
#pragma unroll
    for (int m = 0; m < 2; m++) {
      float sum = 0.f;
      unsigned int u[4][2];
#pragma unroll
      for (int kt = 0; kt < 4; kt++) {
        float e0 = __builtin_amdgcn_exp2f(xs[m][kt][0]);
        float e1 = __builtin_amdgcn_exp2f(xs[m][kt][1]);
        float e2 = __builtin_amdgcn_exp2f(xs[m][kt][2]);
        float e3 = __builtin_amdgcn_exp2f(xs[m][kt][3]);
        sum += (e0 + e1) + (e2 + e3);
        asm("v_cvt_pk_bf16_f32 %0, %1, %2" : "=v"(u[kt][0]) : "v"(e0), "v"(e1));
        asm("v_cvt_pk_bf16_f32 %0, %1, %2" : "=v"(u[kt][1]) : "v"(e2), "v"(e3));
      }
      li[m] += sum;
#pragma unroll
      for (int f = 0; f < 2; f++) {
        unsigned int a0 = u[2 * f][0], b0 = u[2 * f + 1][0];
        unsigned int a1 = u[2 * f][1], b1 = u[2 * f + 1][1];
        // step 1: a(high32) <-> b(low32): a=[a_lo,b_lo] (k3=0), b=[a_hi,b_hi] (k3=1), lane5=k4
        asm("v_permlane32_swap_b32 %0, %1" : "+v"(a0), "+v"(b0));
        asm("v_permlane32_swap_b32 %0, %1" : "+v"(a1), "+v"(b1));
        // step 2: per-32 a(hi16) <-> b(lo16): a: k2=0, b: k2=1, lane4=k3
        asm("v_permlane16_swap_b32 %0, %1" : "+v"(a0), "+v"(b0));
        asm("v_permlane16_swap_b32 %0, %1" : "+v"(a1), "+v"(b1));
        uint4t w;
        w[0] = a0; w[1] = a1; w[2] = b0; w[3] = b1;
        pb[m][f] = __builtin_bit_cast(bf16x8, w);
      }
    }

    // Phase C: O^T += V^T x P^T
    __builtin_amdgcn_s_setprio(1);
#pragma unroll
    for (int dt = 0; dt < 4; dt++) {
      const bf16* vr = Vs + (dt * 16 + l16) * 64;
      bf16x8 v0 = *(const bf16x8*)(vr + xq * 8);
      bf16x8 v1 = *(const bf16x8*)(vr + (xq ^ 4) * 8);
      o[0][dt] = __builtin_amdgcn_mfma_f32_16x16x32_bf16(v0, pb[0][0], o[0][dt], 0, 0, 0);
      o[0][dt] = __builtin_amdgcn_mfma_f32_16x16x32_bf16(v1, pb[0][1], o[0][dt], 0, 0, 0);
      o[1][dt] = __builtin_amdgcn_mfma_f32_16x16x32_bf16(v0, pb[1][0], o[1][dt], 0, 0, 0);
      o[1][dt] = __builtin_amdgcn_mfma_f32_16x16x32_bf16(v1, pb[1][1], o[1][dt], 0, 0, 0);
    }
    __builtin_amdgcn_s_setprio(0);
  }
#pragma unroll
  for (int m = 0; m < 2; m++) {
    li[m] += __shfl_xor(li[m], 16, 64);
    li[m] += __shfl_xor(li[m], 32, 64);
  }
#pragma unroll
  for (int m = 0; m < 2; m++) {
    float inv = 1.0f / li[m];
    float* op = out + ((size_t)b * SQ + q0 + m * 16 + l16) * DMODEL + h * HD;
#pragma unroll
    for (int dt = 0; dt < 4; dt++)
#pragma unroll
      for (int r = 0; r < 4; r++)
        op[dt * 16 + quad * 4 + r] = o[m][dt][r] * inv;
  }
}

// ---------------------------------------------------------------- launcher
extern "C" void kernel_launch(void* const* d_in, const int* in_sizes, int n_in,
                              void* d_out, int out_size, void* d_ws, size_t ws_size,
                              hipStream_t stream) {
  (void)in_sizes; (void)n_in; (void)out_size; (void)ws_size;
  const float* hs   = (const float*)d_in[0];
  const float* mask = (const float*)d_in[1];
  const float* Wq   = (const float*)d_in[2];
  const float* bq   = (const float*)d_in[3];
  const float* Wk   = (const float*)d_in[4];
  const float* bk   = (const float*)d_in[5];
  const float* Wv   = (const float*)d_in[6];
  const float* bv   = (const float*)d_in[7];
  float* out = (float*)d_out;
  char* ws = (char*)d_ws;
  bf16* xb = (bf16*)(ws + XB_OFF);
  bf16* wt = (bf16*)(ws + WT_OFF);
  bf16* q  = (bf16*)(ws + Q_OFF);
  bf16* k  = (bf16*)(ws + K_OFF);
  bf16* v  = (bf16*)(ws + V_OFF);
  int* flg = (int*)(ws + FLG_OFF);

  prep<<<8192 + 3072 + 2048, 256, 0, stream>>>(hs, xb, Wq, Wk, Wv, wt, mask, flg);
  qkv<<<1536, 256, 0, stream>>>(xb, wt, bq, bk, bv, q, k, v);
  attn<<<dim3(64, 16), 256, 0, stream>>>(q, k, v, mask, flg, out);
}

// Round 6
// 289.013 us; speedup vs baseline: 1.9408x; 1.0200x over previous
//
#include <hip/hip_runtime.h>

typedef __bf16 bf16;
typedef __bf16 bf16x8 __attribute__((ext_vector_type(8)));
typedef __bf16 bf16x4 __attribute__((ext_vector_type(4)));
typedef float floatx4 __attribute__((ext_vector_type(4)));
typedef unsigned int uint4t __attribute__((ext_vector_type(4)));

typedef __attribute__((address_space(1))) void gvoid;
typedef __attribute__((address_space(3))) void lvoid;
#define ASYNC_COPY16(gp, lp) \
  __builtin_amdgcn_global_load_lds((gvoid*)(gp), (lvoid*)(lp), 16, 0, 0)

#define NB 4
#define SQ 2048
#define DMODEL 1024
#define NH 16
#define HD 64
#define MTOK (NB * SQ)   // 8192
#define LOG2E 1.44269504088896f

// workspace layout (bytes)
#define XB_OFF 0ull                        // bf16 X       [8192][1024]  16 MB
#define WT_OFF (16ull * 1024 * 1024)       // bf16 W^T x3  [3][1024][1024] 6 MB
#define Q_OFF  (22ull * 1024 * 1024)       // bf16 Q [64][2048][64]  16 MB (pre-scaled 0.125*log2e)
#define K_OFF  (38ull * 1024 * 1024)       // bf16 K [64][2048][64]  16 MB
#define V_OFF  (54ull * 1024 * 1024)       // bf16 V^T [64][64][2048] 16 MB
#define FLG_OFF (70ull * 1024 * 1024)      // int flags [4][16][32]   8 KB

// ------------------------------------------------- prep: convert X + transpose W + mask scan
// v2: X-convert grid-strided — 1024 blocks x 8 float4/thread (was 8192 blocks
// x 1 float4/thread = latency-bound near-empty blocks). W / mask branches
// unchanged (re-based indices). Grid 13312 -> 6144 blocks.
__global__ __launch_bounds__(256) void prep(
    const float* __restrict__ x, bf16* __restrict__ xb,
    const float* __restrict__ w0, const float* __restrict__ w1,
    const float* __restrict__ w2, bf16* __restrict__ wt,
    const float* __restrict__ mask, int* __restrict__ flags) {
  __shared__ float tlds[32][33];
  int blk = blockIdx.x;
  int t = threadIdx.x;
  if (blk < 1024) {
    // X: 8192x1024 f32 -> bf16. 2.097M float4 units; 8 per thread, coalesced.
    size_t base = (size_t)blk * 2048 + t;
    const float4* xin = (const float4*)x;
    bf16x4* xo = (bf16x4*)xb;
#pragma unroll
    for (int j = 0; j < 8; j++) {
      float4 v = xin[base + j * 256];
      bf16x4 o;
      o[0] = (bf16)v.x; o[1] = (bf16)v.y; o[2] = (bf16)v.z; o[3] = (bf16)v.w;
      xo[base + j * 256] = o;
    }
  } else if (blk < 4096) {
    int tidx = blk - 1024;            // 0..3071
    int z = tidx >> 10;               // 0..2
    int rem = tidx & 1023;
    int kb = ((rem >> 5) & 31) * 32, nb = (rem & 31) * 32;
    const float* w = (z == 0) ? w0 : (z == 1) ? w1 : w2;
    bf16* out = wt + (size_t)z * DMODEL * DMODEL;
    int tx = t & 31, ty = t >> 5;     // 32 x 8
#pragma unroll
    for (int i = 0; i < 4; i++)
      tlds[ty + 8 * i][tx] = w[(size_t)(kb + ty + 8 * i) * DMODEL + nb + tx];
    __syncthreads();
#pragma unroll
    for (int i = 0; i < 4; i++)
      out[(size_t)(nb + ty + 8 * i) * DMODEL + kb + tx] = (bf16)tlds[tx][ty + 8 * i];
  } else {
    int midx = blk - 4096;            // 0..2047
    int kt = midx & 31, qt = (midx >> 5) & 15, b = midx >> 9;
    const float* mb = mask + ((size_t)b * SQ + qt * 128) * SQ + kt * 64;
    int row = t >> 1, half = t & 1;
    const float4* p = (const float4*)(mb + (size_t)row * SQ + half * 32);
    bool nz = false;
#pragma unroll
    for (int i = 0; i < 8; i++) {
      float4 vv = p[i];
      nz |= (vv.x != 0.f) | (vv.y != 0.f) | (vv.z != 0.f) | (vv.w != 0.f);
    }
    int* acc = (int*)tlds;
    if (t == 0) acc[0] = 0;
    __syncthreads();
    unsigned long long m = __ballot(nz);
    if ((t & 63) == 0 && m) atomicOr(acc, 1);
    __syncthreads();
    if (t == 0) flags[(b * 16 + qt) * 32 + kt] = acc[0];
  }
}

// ---------------------------------------------------------------- QKV GEMM (pure)
// 1536 blocks = 64 mt x 24 nt; XCD band mapping (id&7 -> mt band) for L2 reuse.
#define BK 64
__global__ __launch_bounds__(256) void qkv(
    const bf16* __restrict__ xb,   // [8192][1024]
    const bf16* __restrict__ wt,   // [3][1024 n][1024 k]
    const float* __restrict__ biasq, const float* __restrict__ biask,
    const float* __restrict__ biasv,
    bf16* __restrict__ q, bf16* __restrict__ k, bf16* __restrict__ v) {
  __shared__ bf16 As[128 * BK];
  __shared__ bf16 Bs[128 * BK];

  int id = blockIdx.x;              // 0..1535
  int local = id >> 3;              // 0..191
  int mt = ((id & 7) << 3) | (local & 7);  // 0..63, band per XCD
  int nt = local >> 3;              // 0..23
  int t = threadIdx.x;

  int mat = nt >> 3;                // 0=Q 1=K 2=V
  int nbase = (nt & 7) * 128;
  const bf16* wmat = wt + (size_t)mat * DMODEL * DMODEL;
  const float* bias = (mat == 0) ? biasq : (mat == 1) ? biask : biasv;
  bf16* outp = (mat == 0) ? q : (mat == 1) ? k : v;

  int lane = t & 63, wid = t >> 6;
  int quad = lane >> 4, l16 = lane & 15;
  int wm = (wid & 1) * 64, wn = (wid >> 1) * 64;
  int xq = quad ^ (l16 & 7);        // swizzled chunk index

  floatx4 acc[4][4] = {};

  for (int kb = 0; kb < DMODEL; kb += BK) {
    __syncthreads();
#pragma unroll
    for (int p = 0; p < 4; p++) {
      int i2 = p * 256 + t;
      int row = i2 >> 3;
      int gch = (i2 ^ row) & 7;
      ASYNC_COPY16(xb + (size_t)(mt * 128 + row) * DMODEL + kb + gch * 8,
                   As + i2 * 8);
      ASYNC_COPY16(wmat + (size_t)(nbase + row) * DMODEL + kb + gch * 8,
                   Bs + i2 * 8);
    }
    __syncthreads();

#pragma unroll
    for (int kc = 0; kc < BK; kc += 32) {
      int xc = (kc >> 3) ^ xq;
      bf16x8 af[4], bfr[4];
#pragma unroll
      for (int mi = 0; mi < 4; mi++)
        af[mi] = *(const bf16x8*)(As + (wm + mi * 16 + l16) * BK + xc * 8);
#pragma unroll
      for (int ni = 0; ni < 4; ni++)
        bfr[ni] = *(const bf16x8*)(Bs + (wn + ni * 16 + l16) * BK + xc * 8);
      if (mat < 2) {   // transposed: D[n][m], col=l16=token
#pragma unroll
        for (int mi = 0; mi < 4; mi++)
#pragma unroll
          for (int ni = 0; ni < 4; ni++)
            acc[mi][ni] = __builtin_amdgcn_mfma_f32_16x16x32_bf16(
                bfr[ni], af[mi], acc[mi][ni], 0, 0, 0);
      } else {         // normal: D[m][n], col=l16=feature
#pragma unroll
        for (int mi = 0; mi < 4; mi++)
#pragma unroll
          for (int ni = 0; ni < 4; ni++)
            acc[mi][ni] = __builtin_amdgcn_mfma_f32_16x16x32_bf16(
                af[mi], bfr[ni], acc[mi][ni], 0, 0, 0);
      }
    }
  }

  int mg0 = mt * 128 + wm;
  if (mat < 2) {
    float qscale = (mat == 0) ? 0.125f * LOG2E : 1.0f;
#pragma unroll
    for (int ni = 0; ni < 4; ni++) {
      int n0 = nbase + wn + ni * 16 + quad * 4;
      int h = n0 >> 6, d0 = n0 & 63;
      float4 bv4 = *(const float4*)(bias + n0);
#pragma unroll
      for (int mi = 0; mi < 4; mi++) {
        int m = mg0 + mi * 16 + l16;
        int b = m >> 11, s = m & 2047;
        bf16x4 pk;
        pk[0] = (bf16)((acc[mi][ni][0] + bv4.x) * qscale);
        pk[1] = (bf16)((acc[mi][ni][1] + bv4.y) * qscale);
        pk[2] = (bf16)((acc[mi][ni][2] + bv4.z) * qscale);
        pk[3] = (bf16)((acc[mi][ni][3] + bv4.w) * qscale);
        *(bf16x4*)(outp + (((size_t)(b * NH + h) * SQ + s) << 6) + d0) = pk;
      }
    }
  } else {
#pragma unroll
    for (int ni = 0; ni < 4; ni++) {
      int n = nbase + wn + ni * 16 + l16;
      int h = n >> 6, d = n & 63;
      float bv_ = bias[n];
#pragma unroll
      for (int mi = 0; mi < 4; mi++) {
        int m0 = mg0 + mi * 16 + quad * 4;
        int b = m0 >> 11, s = m0 & 2047;
        bf16x4 pk;
#pragma unroll
        for (int r = 0; r < 4; r++) pk[r] = (bf16)(acc[mi][ni][r] + bv_);
        *(bf16x4*)(outp + (((size_t)(b * NH + h) * HD + d) << 11) + s) = pk;
      }
    }
  }
}

// ---------------------------------------------------------------- attention
// Single-buffered K/V staging. P transpose IN-REGISTER via
// v_permlane32_swap + v_permlane16_swap (operand order verified round 3/4:
// absmax OK, bank conflicts 0). launch_bounds(256,4): VGPR budget 128 —
// (256,6) spilled the accumulators (1.6 GB scratch traffic). 16.4KB LDS.
__global__ __launch_bounds__(256, 4) void attn(
    const bf16* __restrict__ Q,     // [64][2048][64], pre-scaled by 0.125*log2e
    const bf16* __restrict__ K,     // [64][2048][64]
    const bf16* __restrict__ Vt,    // [64][64][2048]
    const float* __restrict__ mask, // [4][2048][2048]
    const int* __restrict__ flags,  // [4][16][32]
    float* __restrict__ out) {      // [4][2048][1024]
  __shared__ bf16 Ks[64 * 64];      // [s][d], swizzled
  __shared__ bf16 Vs[64 * 64];      // [d][s], swizzled

  int bh = blockIdx.x;              // 0..63 (all qt of one head on one XCD)
  int qt = blockIdx.y;
  int b = bh >> 4, h = bh & 15;
  int t = threadIdx.x, lane = t & 63, wid = t >> 6;
  int quad = lane >> 4, l16 = lane & 15;
  int q0 = qt * 128 + wid * 32;

  const bf16* Qp = Q + ((size_t)bh * SQ + q0) * HD;
  const bf16* Kp = K + (size_t)bh * SQ * HD;
  const bf16* Vp = Vt + (size_t)bh * HD * SQ;
  const float* mp = mask + ((size_t)b * SQ + q0) * SQ;
  const int* flg = flags + (b * 16 + qt) * 32;

  bf16x8 qa[2][2];
#pragma unroll
  for (int m = 0; m < 2; m++) {
    const bf16* qr = Qp + (size_t)(m * 16 + l16) * HD;
    qa[m][0] = *(const bf16x8*)(qr + quad * 8);
    qa[m][1] = *(const bf16x8*)(qr + 32 + quad * 8);
  }

  floatx4 o[2][4] = {};             // O^T[d][q]: col=l16=q, row=quad*4+r=d
  float li[2] = {0.f, 0.f};
  int xq = quad ^ (l16 & 7);

  for (int kb = 0, kti = 0; kb < SQ; kb += 64, kti++) {
    __syncthreads();
#pragma unroll
    for (int p = 0; p < 2; p++) {
      int idx = p * 256 + t;        // 0..511
      int row = idx >> 3;
      int gch = (idx ^ row) & 7;
      ASYNC_COPY16(Kp + (size_t)(kb + row) * HD + gch * 8, Ks + idx * 8);
      ASYNC_COPY16(Vp + (size_t)row * SQ + kb + gch * 8, Vs + idx * 8);
    }
    __syncthreads();
    int flag = flg[kti];

    // Phase A: S^T for both m tiles; xs[m][kt][r] holds k = 16kt + 4quad + r
    float xs[2][4][4];
    __builtin_amdgcn_s_setprio(1);
#pragma unroll
    for (int kt = 0; kt < 4; kt++) {
      const bf16* kr = Ks + (kt * 16 + l16) * 64;
      bf16x8 k0 = *(const bf16x8*)(kr + xq * 8);
      bf16x8 k1 = *(const bf16x8*)(kr + (xq ^ 4) * 8);
      floatx4 z0 = {}, z1 = {};
      z0 = __builtin_amdgcn_mfma_f32_16x16x32_bf16(k0, qa[0][0], z0, 0, 0, 0);
      z0 = __builtin_amdgcn_mfma_f32_16x16x32_bf16(k1, qa[0][1], z0, 0, 0, 0);
      z1 = __builtin_amdgcn_mfma_f32_16x16x32_bf16(k0, qa[1][0], z1, 0, 0, 0);
      z1 = __builtin_amdgcn_mfma_f32_16x16x32_bf16(k1, qa[1][1], z1, 0, 0, 0);
#pragma unroll
      for (int r = 0; r < 4; r++) { xs[0][kt][r] = z0[r]; xs[1][kt][r] = z1[r]; }
    }
    __builtin_amdgcn_s_setprio(0);
    if (flag) {
#pragma unroll
      for (int m = 0; m < 2; m++)
#pragma unroll
        for (int kt = 0; kt < 4; kt++)
#pragma unroll
          for (int r = 0; r < 4; r++)
            xs[m][kt][r] = __builtin_fmaf(
                mp[(size_t)(m * 16 + l16) * SQ + kb + kt * 16 + quad * 4 + r],
                LOG2E, xs[m][kt][r]);
    }

    // Phase B: exp2 -> cvt_pk bf16 pairs -> in-register quad transpose.
    // u[kt][p]: reg bits (k5=kt>>1, k4=kt&1, k1=p), halves k0, lane[5:4]=k[3:2].
    // swap(vdst=a, vsrc=b) twice: lane[5:4] becomes k[4:3], regs (k5,k2,k1).
    bf16x8 pb[2][2];
#pragma unroll
    for (int m = 0; m < 2; m++) {
      float sum = 0.f;
      unsigned int u[4][2];
#pragma unroll
      for (int kt = 0; kt < 4; kt++) {
        float e0 = __builtin_amdgcn_exp2f(xs[m][kt][0]);
        float e1 = __builtin_amdgcn_exp2f(xs[m][kt][1]);
        float e2 = __builtin_amdgcn_exp2f(xs[m][kt][2]);
        float e3 = __builtin_amdgcn_exp2f(xs[m][kt][3]);
        sum += (e0 + e1) + (e2 + e3);
        asm("v_cvt_pk_bf16_f32 %0, %1, %2" : "=v"(u[kt][0]) : "v"(e0), "v"(e1));
        asm("v_cvt_pk_bf16_f32 %0, %1, %2" : "=v"(u[kt][1]) : "v"(e2), "v"(e3));
      }
      li[m] += sum;
#pragma unroll
      for (int f = 0; f < 2; f++) {
        unsigned int a0 = u[2 * f][0], b0 = u[2 * f + 1][0];
        unsigned int a1 = u[2 * f][1], b1 = u[2 * f + 1][1];
        // step 1: a(high32) <-> b(low32): a=[a_lo,b_lo] (k3=0), b=[a_hi,b_hi] (k3=1), lane5=k4
        asm("v_permlane32_swap_b32 %0, %1" : "+v"(a0), "+v"(b0));
        asm("v_permlane32_swap_b32 %0, %1" : "+v"(a1), "+v"(b1));
        // step 2: per-32 a(hi16) <-> b(lo16): a: k2=0, b: k2=1, lane4=k3
        asm("v_permlane16_swap_b32 %0, %1" : "+v"(a0), "+v"(b0));
        asm("v_permlane16_swap_b32 %0, %1" : "+v"(a1), "+v"(b1));
        uint4t w;
        w[0] = a0; w[1] = a1; w[2] = b0; w[3] = b1;
        pb[m][f] = __builtin_bit_cast(bf16x8, w);
      }
    }

    // Phase C: O^T += V^T x P^T
    __builtin_amdgcn_s_setprio(1);
#pragma unroll
    for (int dt = 0; dt < 4; dt++) {
      const bf16* vr = Vs + (dt * 16 + l16) * 64;
      bf16x8 v0 = *(const bf16x8*)(vr + xq * 8);
      bf16x8 v1 = *(const bf16x8*)(vr + (xq ^ 4) * 8);
      o[0][dt] = __builtin_amdgcn_mfma_f32_16x16x32_bf16(v0, pb[0][0], o[0][dt], 0, 0, 0);
      o[0][dt] = __builtin_amdgcn_mfma_f32_16x16x32_bf16(v1, pb[0][1], o[0][dt], 0, 0, 0);
      o[1][dt] = __builtin_amdgcn_mfma_f32_16x16x32_bf16(v0, pb[1][0], o[1][dt], 0, 0, 0);
      o[1][dt] = __builtin_amdgcn_mfma_f32_16x16x32_bf16(v1, pb[1][1], o[1][dt], 0, 0, 0);
    }
    __builtin_amdgcn_s_setprio(0);
  }
#pragma unroll
  for (int m = 0; m < 2; m++) {
    li[m] += __shfl_xor(li[m], 16, 64);
    li[m] += __shfl_xor(li[m], 32, 64);
  }
#pragma unroll
  for (int m = 0; m < 2; m++) {
    float inv = 1.0f / li[m];
    float* op = out + ((size_t)b * SQ + q0 + m * 16 + l16) * DMODEL + h * HD;
#pragma unroll
    for (int dt = 0; dt < 4; dt++)
#pragma unroll
      for (int r = 0; r < 4; r++)
        op[dt * 16 + quad * 4 + r] = o[m][dt][r] * inv;
  }
}

// ---------------------------------------------------------------- launcher
extern "C" void kernel_launch(void* const* d_in, const int* in_sizes, int n_in,
                              void* d_out, int out_size, void* d_ws, size_t ws_size,
                              hipStream_t stream) {
  (void)in_sizes; (void)n_in; (void)out_size; (void)ws_size;
  const float* hs   = (const float*)d_in[0];
  const float* mask = (const float*)d_in[1];
  const float* Wq   = (const float*)d_in[2];
  const float* bq   = (const float*)d_in[3];
  const float* Wk   = (const float*)d_in[4];
  const float* bk   = (const float*)d_in[5];
  const float* Wv   = (const float*)d_in[6];
  const float* bv   = (const float*)d_in[7];
  float* out = (float*)d_out;
  char* ws = (char*)d_ws;
  bf16* xb = (bf16*)(ws + XB_OFF);
  bf16* wt = (bf16*)(ws + WT_OFF);
  bf16* q  = (bf16*)(ws + Q_OFF);
  bf16* k  = (bf16*)(ws + K_OFF);
  bf16* v  = (bf16*)(ws + V_OFF);
  int* flg = (int*)(ws + FLG_OFF);

  prep<<<1024 + 3072 + 2048, 256, 0, stream>>>(hs, xb, Wq, Wk, Wv, wt, mask, flg);
  qkv<<<1536, 256, 0, stream>>>(xb, wt, bq, bk, bv, q, k, v);
  attn<<<dim3(64, 16), 256, 0, stream>>>(q, k, v, mask, flg, out);
}